// Round 5
// baseline (197.112 us; speedup 1.0000x reference)
//
#include <hip/hip_runtime.h>
#include <hip/hip_bf16.h>
#include <stdint.h>

#define B_ 2
#define L_ 1024
#define D_ 1024
#define H_ 16
#define W_ 64
#define DH_ 64

typedef __attribute__((ext_vector_type(8))) __bf16 bf16x8;
typedef __attribute__((ext_vector_type(4))) float floatx4;

#define AS3(p) ((__attribute__((address_space(3))) void*)(p))
#define AS1(p) ((const __attribute__((address_space(1))) void*)(p))

static __device__ __forceinline__ ushort f2bf(float f) {
    union { float f; uint32_t u; } v{f};
    uint32_t r = v.u + 0x7fff + ((v.u >> 16) & 1);  // RNE
    return (ushort)(r >> 16);
}
static __device__ __forceinline__ uint32_t pack2(float a, float b) {
    return (uint32_t)f2bf(a) | ((uint32_t)f2bf(b) << 16);
}

// ---------------- convert fp32 -> bf16 for x and the four weights ----------------
__global__ __launch_bounds__(256) void cvt_inputs(
    const float* __restrict__ x, const float* __restrict__ wq, const float* __restrict__ wk,
    const float* __restrict__ wv, const float* __restrict__ wo,
    ushort* __restrict__ xb, ushort* __restrict__ wqb, ushort* __restrict__ wkb,
    ushort* __restrict__ wvb, ushort* __restrict__ wob) {
    const size_t M1 = 1u << 20;
    size_t i4 = ((size_t)blockIdx.x * 256 + threadIdx.x) * 4;
    const float* s; ushort* d; size_t off;
    if (i4 < 2 * M1)      { s = x;  d = xb;  off = i4; }
    else if (i4 < 3 * M1) { s = wq; d = wqb; off = i4 - 2 * M1; }
    else if (i4 < 4 * M1) { s = wk; d = wkb; off = i4 - 3 * M1; }
    else if (i4 < 5 * M1) { s = wv; d = wvb; off = i4 - 4 * M1; }
    else                  { s = wo; d = wob; off = i4 - 5 * M1; }
    float4 f = *(const float4*)(s + off);
    ushort4 o;
    o.x = f2bf(f.x); o.y = f2bf(f.y); o.z = f2bf(f.z); o.w = f2bf(f.w);
    *(ushort4*)(d + off) = o;
}

// ---------------- fused QKV GEMM: q/k/v = x @ W^T, head-major bf16 out ----------------
// 128x128 tile, BK=64, XOR-swizzled LDS, register-prefetch software pipeline:
// global->VGPR loads for tile k+1 issued BEFORE computing tile k (hides load latency).
#define BK 64

__global__ __launch_bounds__(256) void gemm_qkv(
    const ushort* __restrict__ xb,   // 2048 x 1024 bf16, K-major
    const ushort* __restrict__ wqb, const ushort* __restrict__ wkb, const ushort* __restrict__ wvb,
    ushort* __restrict__ q, ushort* __restrict__ k, ushort* __restrict__ v) {  // (B,H,L,DH) bf16
    __shared__ __align__(16) ushort As[128 * BK];
    __shared__ __align__(16) ushort Bs[128 * BK];
    const int tid = threadIdx.x;
    const int m0 = blockIdx.x * 128;
    const int nt = blockIdx.y;          // 0..23
    const int which = nt >> 3;
    const int n0 = (nt & 7) * 128;
    const ushort* wsel = which == 0 ? wqb : (which == 1 ? wkb : wvb);
    ushort* dsel = which == 0 ? q : (which == 1 ? k : v);

    const int lane = tid & 63;
    const int wv_ = tid >> 6;
    const int wm = (wv_ & 1) * 64;
    const int wn = (wv_ >> 1) * 64;
    const int lr = lane & 15;
    const int quad = lane >> 4;

    floatx4 acc[4][4];
#pragma unroll
    for (int i = 0; i < 4; ++i)
#pragma unroll
        for (int j = 0; j < 4; ++j) acc[i][j] = (floatx4){0.f, 0.f, 0.f, 0.f};

    // chunk c = tid + it*256 -> row r=c>>3, phys slot s=c&7, global k-chunk g = s^(r&7)
    int offA[4], offB[4];
#pragma unroll
    for (int it = 0; it < 4; ++it) {
        int c = tid + it * 256;
        int r = c >> 3, s = c & 7, g = s ^ (r & 7);
        offA[it] = (m0 + r) * 1024 + g * 8;
        offB[it] = (n0 + r) * 1024 + g * 8;
    }

    uint4 ra[4], rb[4];
#pragma unroll
    for (int it = 0; it < 4; ++it) {
        ra[it] = *(const uint4*)(xb + offA[it]);
        rb[it] = *(const uint4*)(wsel + offB[it]);
    }
#pragma unroll
    for (int it = 0; it < 4; ++it) {
        *(uint4*)(As + (it * 256 + tid) * 8) = ra[it];
        *(uint4*)(Bs + (it * 256 + tid) * 8) = rb[it];
    }
    __syncthreads();

    for (int k0 = 0; k0 < 1024; k0 += BK) {
        const bool more = (k0 + BK) < 1024;
        if (more) {
#pragma unroll
            for (int it = 0; it < 4; ++it) {
                ra[it] = *(const uint4*)(xb + offA[it] + k0 + BK);
                rb[it] = *(const uint4*)(wsel + offB[it] + k0 + BK);
            }
        }
#pragma unroll
        for (int ks = 0; ks < 2; ++ks) {
            bf16x8 af[4], bfr[4];
#pragma unroll
            for (int i = 0; i < 4; ++i) {
                int r = wm + i * 16 + lr;
                af[i] = *(const bf16x8*)(As + r * BK + (((ks * 4 + quad) ^ (r & 7)) * 8));
            }
#pragma unroll
            for (int j = 0; j < 4; ++j) {
                int r = wn + j * 16 + lr;
                bfr[j] = *(const bf16x8*)(Bs + r * BK + (((ks * 4 + quad) ^ (r & 7)) * 8));
            }
#pragma unroll
            for (int i = 0; i < 4; ++i)
#pragma unroll
                for (int j = 0; j < 4; ++j)
                    acc[i][j] = __builtin_amdgcn_mfma_f32_16x16x32_bf16(af[i], bfr[j], acc[i][j], 0, 0, 0);
        }
        __syncthreads();   // everyone done reading LDS
        if (more) {
#pragma unroll
            for (int it = 0; it < 4; ++it) {
                *(uint4*)(As + (it * 256 + tid) * 8) = ra[it];
                *(uint4*)(Bs + (it * 256 + tid) * 8) = rb[it];
            }
        }
        __syncthreads();   // writes visible
    }

#pragma unroll
    for (int i = 0; i < 4; ++i) {
        int rbase = m0 + wm + i * 16 + quad * 4;
#pragma unroll
        for (int j = 0; j < 4; ++j) {
            int c = n0 + wn + j * 16 + lr;
            int h = c >> 6, dh = c & 63;
#pragma unroll
            for (int r = 0; r < 4; ++r) {
                int m = rbase + r;
                int bb = m >> 10, l = m & 1023;
                dsel[(((size_t)bb * 16 + h) * 1024 + l) * 64 + dh] = f2bf(acc[i][j][r]);
            }
        }
    }
}

// ---------------- Wo GEMM: out = ao @ Wo^T, fp32 out. 128x64, register-prefetch pipeline ----------------
__global__ __launch_bounds__(256) void gemm_wo(
    const ushort* __restrict__ ab,   // 2048 x 1024 bf16
    const ushort* __restrict__ wob,
    float* __restrict__ out) {
    __shared__ __align__(16) ushort As[128 * BK];
    __shared__ __align__(16) ushort Bs[64 * BK];
    const int tid = threadIdx.x;
    const int m0 = blockIdx.x * 128;
    const int n0 = blockIdx.y * 64;
    const int lane = tid & 63;
    const int wv_ = tid >> 6;
    const int wm = (wv_ & 1) * 64;
    const int wn = (wv_ >> 1) * 32;
    const int lr = lane & 15;
    const int quad = lane >> 4;

    floatx4 acc[4][2];
#pragma unroll
    for (int i = 0; i < 4; ++i)
#pragma unroll
        for (int j = 0; j < 2; ++j) acc[i][j] = (floatx4){0.f, 0.f, 0.f, 0.f};

    int offA[4], offB[2];
#pragma unroll
    for (int it = 0; it < 4; ++it) {
        int c = tid + it * 256;
        int r = c >> 3, s = c & 7, g = s ^ (r & 7);
        offA[it] = (m0 + r) * 1024 + g * 8;
    }
#pragma unroll
    for (int it = 0; it < 2; ++it) {
        int c = tid + it * 256;
        int r = c >> 3, s = c & 7, g = s ^ (r & 7);
        offB[it] = (n0 + r) * 1024 + g * 8;
    }

    uint4 ra[4], rb[2];
#pragma unroll
    for (int it = 0; it < 4; ++it) ra[it] = *(const uint4*)(ab + offA[it]);
#pragma unroll
    for (int it = 0; it < 2; ++it) rb[it] = *(const uint4*)(wob + offB[it]);
#pragma unroll
    for (int it = 0; it < 4; ++it) *(uint4*)(As + (it * 256 + tid) * 8) = ra[it];
#pragma unroll
    for (int it = 0; it < 2; ++it) *(uint4*)(Bs + (it * 256 + tid) * 8) = rb[it];
    __syncthreads();

    for (int k0 = 0; k0 < 1024; k0 += BK) {
        const bool more = (k0 + BK) < 1024;
        if (more) {
#pragma unroll
            for (int it = 0; it < 4; ++it) ra[it] = *(const uint4*)(ab + offA[it] + k0 + BK);
#pragma unroll
            for (int it = 0; it < 2; ++it) rb[it] = *(const uint4*)(wob + offB[it] + k0 + BK);
        }
#pragma unroll
        for (int ks = 0; ks < 2; ++ks) {
            bf16x8 af[4], bfr[2];
#pragma unroll
            for (int i = 0; i < 4; ++i) {
                int r = wm + i * 16 + lr;
                af[i] = *(const bf16x8*)(As + r * BK + (((ks * 4 + quad) ^ (r & 7)) * 8));
            }
#pragma unroll
            for (int j = 0; j < 2; ++j) {
                int r = wn + j * 16 + lr;
                bfr[j] = *(const bf16x8*)(Bs + r * BK + (((ks * 4 + quad) ^ (r & 7)) * 8));
            }
#pragma unroll
            for (int i = 0; i < 4; ++i)
#pragma unroll
                for (int j = 0; j < 2; ++j)
                    acc[i][j] = __builtin_amdgcn_mfma_f32_16x16x32_bf16(af[i], bfr[j], acc[i][j], 0, 0, 0);
        }
        __syncthreads();
        if (more) {
#pragma unroll
            for (int it = 0; it < 4; ++it) *(uint4*)(As + (it * 256 + tid) * 8) = ra[it];
#pragma unroll
            for (int it = 0; it < 2; ++it) *(uint4*)(Bs + (it * 256 + tid) * 8) = rb[it];
        }
        __syncthreads();
    }

#pragma unroll
    for (int i = 0; i < 4; ++i) {
        int rbase = m0 + wm + i * 16 + quad * 4;
#pragma unroll
        for (int j = 0; j < 2; ++j) {
            int c = n0 + wn + j * 16 + lr;
#pragma unroll
            for (int r = 0; r < 4; ++r)
                out[(size_t)(rbase + r) * 1024 + c] = acc[i][j][r];
        }
    }
}

// ---------------- banded attention via MFMA (flash-style, one 64-query tile/block) ----------------
#define STRQ 72    // LDS row stride (ushorts) for 64-wide rows
#define STRV 136   // LDS row stride for 128-wide rows

__global__ __launch_bounds__(256) void band_attn3(
    const ushort* __restrict__ q,    // (B,H,L,DH) bf16
    const ushort* __restrict__ k,
    const ushort* __restrict__ v,
    const float* __restrict__ lastk, // (63,H,DH) fp32
    const float* __restrict__ lastv,
    ushort* __restrict__ ao) {       // (B,L,D) bf16 row-major
    __shared__ __align__(16) ushort Qs[64 * STRQ];
    __shared__ __align__(16) ushort Kw[128 * STRQ];
    __shared__ __align__(16) ushort Vt[64 * STRV];   // V^T: Vt[d][j]
    __shared__ __align__(16) ushort Ps[64 * STRV];   // P: row i, col j (A-layout for PV)
    const int tid = threadIdx.x;
    const int lane = tid & 63;
    const int wid = tid >> 6;
    const int l0 = blockIdx.x * 64;
    const int b = blockIdx.y >> 4, h = blockIdx.y & 15;
    const size_t hb = (size_t)(b * 16 + h) * 1024 * 64;

    // ---- stage Q (64x64) ----
#pragma unroll
    for (int it = 0; it < 2; ++it) {
        int c = tid + it * 256;
        int rr = c >> 3, cc = (c & 7) * 8;
        *(uint4*)(Qs + rr * STRQ + cc) = *(const uint4*)(q + hb + (size_t)(l0 + rr) * 64 + cc);
    }
    // ---- stage K window rows j=0..126 (pos = l0+j-63), row 127 zero ----
#pragma unroll
    for (int it = 0; it < 4; ++it) {
        int c = tid + it * 256;
        int j = c >> 3, cc = (c & 7) * 8;
        int pos = l0 + j - 63;
        uint4 t = {0u, 0u, 0u, 0u};
        if (j < 127) {
            if (pos >= 0) {
                t = *(const uint4*)(k + hb + (size_t)pos * 64 + cc);
            } else {                                  // only l0==0, j in [0,62]
                const float* sk = lastk + ((size_t)j * 16 + h) * 64 + cc;
                float4 a0 = *(const float4*)sk, a1 = *(const float4*)(sk + 4);
                t.x = pack2(a0.x, a0.y); t.y = pack2(a0.z, a0.w);
                t.z = pack2(a1.x, a1.y); t.w = pack2(a1.z, a1.w);
            }
        }
        *(uint4*)(Kw + j * STRQ + cc) = t;
    }
    // ---- stage V window TRANSPOSED: Vt[d][j] ----
#pragma unroll
    for (int it = 0; it < 4; ++it) {
        int c = tid + it * 256;
        int j = c >> 3, d8 = (c & 7) * 8;
        int pos = l0 + j - 63;
        ushort tv[8];
        if (j >= 127) {
#pragma unroll
            for (int t = 0; t < 8; ++t) tv[t] = 0;
        } else if (pos >= 0) {
            union { uint4 u4; ushort us[8]; } tu;
            tu.u4 = *(const uint4*)(v + hb + (size_t)pos * 64 + d8);
#pragma unroll
            for (int t = 0; t < 8; ++t) tv[t] = tu.us[t];
        } else {
            const float* sv = lastv + ((size_t)j * 16 + h) * 64 + d8;
#pragma unroll
            for (int t = 0; t < 8; ++t) tv[t] = f2bf(sv[t]);
        }
#pragma unroll
        for (int t = 0; t < 8; ++t) Vt[(size_t)(d8 + t) * STRV + j] = tv[t];
    }
    __syncthreads();

    const int lr = lane & 15;
    const int quad = lane >> 4;

    // ---- scores: S = Q @ Kw^T  (m=16 rows/wave, n=128, k=64) ----
    floatx4 sa[8];
#pragma unroll
    for (int nt = 0; nt < 8; ++nt) sa[nt] = (floatx4){0.f, 0.f, 0.f, 0.f};
    bf16x8 aq[2];
#pragma unroll
    for (int ks = 0; ks < 2; ++ks)
        aq[ks] = *(const bf16x8*)(Qs + (wid * 16 + lr) * STRQ + ks * 32 + quad * 8);
#pragma unroll
    for (int ks = 0; ks < 2; ++ks)
#pragma unroll
        for (int nt = 0; nt < 8; ++nt) {
            bf16x8 bk = *(const bf16x8*)(Kw + (nt * 16 + lr) * STRQ + ks * 32 + quad * 8);
            sa[nt] = __builtin_amdgcn_mfma_f32_16x16x32_bf16(aq[ks], bk, sa[nt], 0, 0, 0);
        }

    // ---- in-register masked softmax; write P (bf16) to LDS in A-layout ----
#pragma unroll
    for (int rr = 0; rr < 4; ++rr) {
        int i_loc = wid * 16 + quad * 4 + rr;   // local query index (0..63)
        float sv[8];
        float mv = -1e30f;
#pragma unroll
        for (int nt = 0; nt < 8; ++nt) {
            int j = nt * 16 + lr;
            int w = j - i_loc;
            sv[nt] = (w >= 0 && w < 64) ? sa[nt][rr] * 0.125f : -1e30f;
            mv = fmaxf(mv, sv[nt]);
        }
#pragma unroll
        for (int off = 8; off; off >>= 1) mv = fmaxf(mv, __shfl_xor(mv, off, 16));
        float sum = 0.f;
#pragma unroll
        for (int nt = 0; nt < 8; ++nt) {
            sv[nt] = __expf(sv[nt] - mv);
            sum += sv[nt];
        }
#pragma unroll
        for (int off = 8; off; off >>= 1) sum += __shfl_xor(sum, off, 16);
        float inv = 1.f / sum;
#pragma unroll
        for (int nt = 0; nt < 8; ++nt)
            Ps[(size_t)i_loc * STRV + nt * 16 + lr] = f2bf(sv[nt] * inv);
    }
    // PV reads only rows wid*16..+15 of Ps — written by this same wave; no barrier needed.

    // ---- O = P @ Vw  (as NT: B = Vt[d][j]) ----
    floatx4 oa[4];
#pragma unroll
    for (int nt = 0; nt < 4; ++nt) oa[nt] = (floatx4){0.f, 0.f, 0.f, 0.f};
#pragma unroll
    for (int ks = 0; ks < 4; ++ks) {
        bf16x8 ap = *(const bf16x8*)(Ps + (wid * 16 + lr) * STRV + ks * 32 + quad * 8);
#pragma unroll
        for (int nt = 0; nt < 4; ++nt) {
            bf16x8 bv = *(const bf16x8*)(Vt + (nt * 16 + lr) * STRV + ks * 32 + quad * 8);
            oa[nt] = __builtin_amdgcn_mfma_f32_16x16x32_bf16(ap, bv, oa[nt], 0, 0, 0);
        }
    }

    // ---- store O: ao[b][l0+i][h*64+d] bf16 ----
#pragma unroll
    for (int nt = 0; nt < 4; ++nt) {
        int d = nt * 16 + lr;
#pragma unroll
        for (int rr = 0; rr < 4; ++rr) {
            int i_loc = wid * 16 + quad * 4 + rr;
            ao[((size_t)b * 1024 + l0 + i_loc) * 1024 + h * 64 + d] = f2bf(oa[nt][rr]);
        }
    }
}

extern "C" void kernel_launch(void* const* d_in, const int* in_sizes, int n_in,
                              void* d_out, int out_size, void* d_ws, size_t ws_size,
                              hipStream_t stream) {
    const float* x     = (const float*)d_in[0];
    const float* Wq    = (const float*)d_in[1];
    const float* Wk    = (const float*)d_in[2];
    const float* Wv    = (const float*)d_in[3];
    const float* Wo    = (const float*)d_in[4];
    const float* lastk = (const float*)d_in[5];
    const float* lastv = (const float*)d_in[6];
    float* out = (float*)d_out;

    const size_t M1 = 1u << 20;
    ushort* xb  = (ushort*)d_ws;          // 2M
    ushort* wqb = xb + 2 * M1;            // 1M
    ushort* wkb = wqb + M1;
    ushort* wvb = wkb + M1;
    ushort* wob = wvb + M1;
    ushort* qh  = wob + M1;               // 2M each, head-major (B,H,L,DH)
    ushort* kh  = qh + 2 * M1;
    ushort* vh  = kh + 2 * M1;
    ushort* ao  = vh + 2 * M1;            // 2M, row-major (B,L,D)

    cvt_inputs<<<6144, 256, 0, stream>>>(x, Wq, Wk, Wv, Wo, xb, wqb, wkb, wvb, wob);
    gemm_qkv<<<dim3(16, 24), 256, 0, stream>>>(xb, wqb, wkb, wvb, qh, kh, vh);
    band_attn3<<<dim3(16, 32), 256, 0, stream>>>(qh, kh, vh, lastk, lastv, ao);
    gemm_wo<<<dim3(16, 16), 256, 0, stream>>>(ao, wob, out);
}

// Round 6
// 121.172 us; speedup vs baseline: 1.6267x; 1.6267x over previous
//
#include <hip/hip_runtime.h>
#include <hip/hip_bf16.h>
#include <stdint.h>

#define B_ 2
#define L_ 1024
#define D_ 1024
#define H_ 16
#define W_ 64
#define DH_ 64

typedef __attribute__((ext_vector_type(8))) __bf16 bf16x8;
typedef __attribute__((ext_vector_type(4))) float floatx4;

#define AS3(p) ((__attribute__((address_space(3))) void*)(p))
#define AS1(p) ((const __attribute__((address_space(1))) void*)(p))

static __device__ __forceinline__ ushort f2bf(float f) {
    union { float f; uint32_t u; } v{f};
    uint32_t r = v.u + 0x7fff + ((v.u >> 16) & 1);  // RNE
    return (ushort)(r >> 16);
}
static __device__ __forceinline__ uint32_t pack2(float a, float b) {
    return (uint32_t)f2bf(a) | ((uint32_t)f2bf(b) << 16);
}

// ---------------- convert fp32 -> bf16 for x and the four weights ----------------
__global__ __launch_bounds__(256) void cvt_inputs(
    const float* __restrict__ x, const float* __restrict__ wq, const float* __restrict__ wk,
    const float* __restrict__ wv, const float* __restrict__ wo,
    ushort* __restrict__ xb, ushort* __restrict__ wqb, ushort* __restrict__ wkb,
    ushort* __restrict__ wvb, ushort* __restrict__ wob) {
    const size_t M1 = 1u << 20;
    size_t i4 = ((size_t)blockIdx.x * 256 + threadIdx.x) * 4;
    const float* s; ushort* d; size_t off;
    if (i4 < 2 * M1)      { s = x;  d = xb;  off = i4; }
    else if (i4 < 3 * M1) { s = wq; d = wqb; off = i4 - 2 * M1; }
    else if (i4 < 4 * M1) { s = wk; d = wkb; off = i4 - 3 * M1; }
    else if (i4 < 5 * M1) { s = wv; d = wvb; off = i4 - 4 * M1; }
    else                  { s = wo; d = wob; off = i4 - 5 * M1; }
    float4 f = *(const float4*)(s + off);
    ushort4 o;
    o.x = f2bf(f.x); o.y = f2bf(f.y); o.z = f2bf(f.z); o.w = f2bf(f.w);
    *(ushort4*)(d + off) = o;
}

// ---------------- fused QKV GEMM: q/k/v = x @ W^T, head-major bf16 out ----------------
// 128x64 tile (768 blocks = 3/CU for latency hiding), BK=64, XOR-swizzled LDS,
// global_load_lds staging (R4 structure — register-prefetch variant regressed 2x in R5).
#define BK 64

__global__ __launch_bounds__(256) void gemm_qkv(
    const ushort* __restrict__ xb,   // 2048 x 1024 bf16, K-major
    const ushort* __restrict__ wqb, const ushort* __restrict__ wkb, const ushort* __restrict__ wvb,
    ushort* __restrict__ q, ushort* __restrict__ k, ushort* __restrict__ v) {  // (B,H,L,DH) bf16
    __shared__ __align__(16) ushort As[128 * BK];   // 16 KB
    __shared__ __align__(16) ushort Bs[64 * BK];    // 8 KB
    const int tid = threadIdx.x;
    const int m0 = blockIdx.x * 128;
    const int nt = blockIdx.y;          // 0..47
    const int which = nt >> 4;          // 0=q 1=k 2=v
    const int n0 = (nt & 15) * 64;
    const ushort* wsel = which == 0 ? wqb : (which == 1 ? wkb : wvb);
    ushort* dsel = which == 0 ? q : (which == 1 ? k : v);

    const int lane = tid & 63;
    const int wv_ = tid >> 6;
    const int wm = (wv_ & 1) * 64;
    const int wn = (wv_ >> 1) * 32;
    const int lr = lane & 15;
    const int quad = lane >> 4;

    floatx4 acc[4][2];
#pragma unroll
    for (int i = 0; i < 4; ++i)
#pragma unroll
        for (int j = 0; j < 2; ++j) acc[i][j] = (floatx4){0.f, 0.f, 0.f, 0.f};

    // chunk c -> row r=c>>3, phys slot s=c&7, global k-chunk g = s^(r&7)
    int offA[4], offB[2];
#pragma unroll
    for (int it = 0; it < 4; ++it) {
        int c = tid + it * 256;
        int r = c >> 3, s = c & 7, g = s ^ (r & 7);
        offA[it] = (m0 + r) * 1024 + g * 8;
    }
#pragma unroll
    for (int it = 0; it < 2; ++it) {
        int c = tid + it * 256;
        int r = c >> 3, s = c & 7, g = s ^ (r & 7);
        offB[it] = (n0 + r) * 1024 + g * 8;
    }

    for (int k0 = 0; k0 < 1024; k0 += BK) {
#pragma unroll
        for (int it = 0; it < 4; ++it)
            __builtin_amdgcn_global_load_lds(AS1(xb + offA[it] + k0), AS3(As + (it * 256 + tid) * 8), 16, 0, 0);
#pragma unroll
        for (int it = 0; it < 2; ++it)
            __builtin_amdgcn_global_load_lds(AS1(wsel + offB[it] + k0), AS3(Bs + (it * 256 + tid) * 8), 16, 0, 0);
        __syncthreads();
#pragma unroll
        for (int ks = 0; ks < 2; ++ks) {
            bf16x8 af[4], bfr[2];
#pragma unroll
            for (int i = 0; i < 4; ++i) {
                int r = wm + i * 16 + lr;
                af[i] = *(const bf16x8*)(As + r * BK + (((ks * 4 + quad) ^ (r & 7)) * 8));
            }
#pragma unroll
            for (int j = 0; j < 2; ++j) {
                int r = wn + j * 16 + lr;
                bfr[j] = *(const bf16x8*)(Bs + r * BK + (((ks * 4 + quad) ^ (r & 7)) * 8));
            }
#pragma unroll
            for (int i = 0; i < 4; ++i)
#pragma unroll
                for (int j = 0; j < 2; ++j)
                    acc[i][j] = __builtin_amdgcn_mfma_f32_16x16x32_bf16(af[i], bfr[j], acc[i][j], 0, 0, 0);
        }
        __syncthreads();
    }

#pragma unroll
    for (int i = 0; i < 4; ++i) {
        int rbase = m0 + wm + i * 16 + quad * 4;
#pragma unroll
        for (int j = 0; j < 2; ++j) {
            int c = n0 + wn + j * 16 + lr;
            int h = c >> 6, dh = c & 63;
#pragma unroll
            for (int r = 0; r < 4; ++r) {
                int m = rbase + r;
                int bb = m >> 10, l = m & 1023;
                dsel[(((size_t)bb * 16 + h) * 1024 + l) * 64 + dh] = f2bf(acc[i][j][r]);
            }
        }
    }
}

// ---------------- Wo GEMM: out = ao @ Wo^T, fp32 out. 64x64 tile (512 blocks = 2/CU) ----------------
__global__ __launch_bounds__(256) void gemm_wo(
    const ushort* __restrict__ ab,   // 2048 x 1024 bf16
    const ushort* __restrict__ wob,
    float* __restrict__ out) {
    __shared__ __align__(16) ushort As[64 * BK];   // 8 KB
    __shared__ __align__(16) ushort Bs[64 * BK];   // 8 KB
    const int tid = threadIdx.x;
    const int m0 = blockIdx.x * 64;
    const int n0 = blockIdx.y * 64;
    const int lane = tid & 63;
    const int wv_ = tid >> 6;
    const int wm = wv_ * 16;           // each wave: 16 m-rows x 64 n-cols
    const int lr = lane & 15;
    const int quad = lane >> 4;

    floatx4 acc[4];
#pragma unroll
    for (int j = 0; j < 4; ++j) acc[j] = (floatx4){0.f, 0.f, 0.f, 0.f};

    int offA[2], offB[2];
#pragma unroll
    for (int it = 0; it < 2; ++it) {
        int c = tid + it * 256;
        int r = c >> 3, s = c & 7, g = s ^ (r & 7);
        offA[it] = (m0 + r) * 1024 + g * 8;
        offB[it] = (n0 + r) * 1024 + g * 8;
    }

    for (int k0 = 0; k0 < 1024; k0 += BK) {
#pragma unroll
        for (int it = 0; it < 2; ++it)
            __builtin_amdgcn_global_load_lds(AS1(ab + offA[it] + k0), AS3(As + (it * 256 + tid) * 8), 16, 0, 0);
#pragma unroll
        for (int it = 0; it < 2; ++it)
            __builtin_amdgcn_global_load_lds(AS1(wob + offB[it] + k0), AS3(Bs + (it * 256 + tid) * 8), 16, 0, 0);
        __syncthreads();
#pragma unroll
        for (int ks = 0; ks < 2; ++ks) {
            int ra = wm + lr;
            bf16x8 af = *(const bf16x8*)(As + ra * BK + (((ks * 4 + quad) ^ (ra & 7)) * 8));
            bf16x8 bfr[4];
#pragma unroll
            for (int j = 0; j < 4; ++j) {
                int r = j * 16 + lr;
                bfr[j] = *(const bf16x8*)(Bs + r * BK + (((ks * 4 + quad) ^ (r & 7)) * 8));
            }
#pragma unroll
            for (int j = 0; j < 4; ++j)
                acc[j] = __builtin_amdgcn_mfma_f32_16x16x32_bf16(af, bfr[j], acc[j], 0, 0, 0);
        }
        __syncthreads();
    }

#pragma unroll
    for (int j = 0; j < 4; ++j) {
        int c = n0 + j * 16 + lr;
#pragma unroll
        for (int r = 0; r < 4; ++r) {
            int m = m0 + wm + quad * 4 + r;
            out[(size_t)m * 1024 + c] = acc[j][r];
        }
    }
}

// ---------------- banded attention via MFMA (flash-style, one 64-query tile/block) ----------------
#define STRQ 72    // LDS row stride (ushorts) for 64-wide rows
#define STRV 136   // LDS row stride for 128-wide rows

__global__ __launch_bounds__(256) void band_attn3(
    const ushort* __restrict__ q,    // (B,H,L,DH) bf16
    const ushort* __restrict__ k,
    const ushort* __restrict__ v,
    const float* __restrict__ lastk, // (63,H,DH) fp32
    const float* __restrict__ lastv,
    ushort* __restrict__ ao) {       // (B,L,D) bf16 row-major
    __shared__ __align__(16) ushort Qs[64 * STRQ];
    __shared__ __align__(16) ushort Kw[128 * STRQ];
    __shared__ __align__(16) ushort Vt[64 * STRV];   // V^T: Vt[d][j]
    __shared__ __align__(16) ushort Ps[64 * STRV];   // P: row i, col j (A-layout for PV)
    const int tid = threadIdx.x;
    const int lane = tid & 63;
    const int wid = tid >> 6;
    const int l0 = blockIdx.x * 64;
    const int b = blockIdx.y >> 4, h = blockIdx.y & 15;
    const size_t hb = (size_t)(b * 16 + h) * 1024 * 64;

    // ---- stage Q (64x64) ----
#pragma unroll
    for (int it = 0; it < 2; ++it) {
        int c = tid + it * 256;
        int rr = c >> 3, cc = (c & 7) * 8;
        *(uint4*)(Qs + rr * STRQ + cc) = *(const uint4*)(q + hb + (size_t)(l0 + rr) * 64 + cc);
    }
    // ---- stage K window rows j=0..126 (pos = l0+j-63), row 127 zero ----
#pragma unroll
    for (int it = 0; it < 4; ++it) {
        int c = tid + it * 256;
        int j = c >> 3, cc = (c & 7) * 8;
        int pos = l0 + j - 63;
        uint4 t = {0u, 0u, 0u, 0u};
        if (j < 127) {
            if (pos >= 0) {
                t = *(const uint4*)(k + hb + (size_t)pos * 64 + cc);
            } else {                                  // only l0==0, j in [0,62]
                const float* sk = lastk + ((size_t)j * 16 + h) * 64 + cc;
                float4 a0 = *(const float4*)sk, a1 = *(const float4*)(sk + 4);
                t.x = pack2(a0.x, a0.y); t.y = pack2(a0.z, a0.w);
                t.z = pack2(a1.x, a1.y); t.w = pack2(a1.z, a1.w);
            }
        }
        *(uint4*)(Kw + j * STRQ + cc) = t;
    }
    // ---- stage V window TRANSPOSED: Vt[d][j] ----
#pragma unroll
    for (int it = 0; it < 4; ++it) {
        int c = tid + it * 256;
        int j = c >> 3, d8 = (c & 7) * 8;
        int pos = l0 + j - 63;
        ushort tv[8];
        if (j >= 127) {
#pragma unroll
            for (int t = 0; t < 8; ++t) tv[t] = 0;
        } else if (pos >= 0) {
            union { uint4 u4; ushort us[8]; } tu;
            tu.u4 = *(const uint4*)(v + hb + (size_t)pos * 64 + d8);
#pragma unroll
            for (int t = 0; t < 8; ++t) tv[t] = tu.us[t];
        } else {
            const float* sv = lastv + ((size_t)j * 16 + h) * 64 + d8;
#pragma unroll
            for (int t = 0; t < 8; ++t) tv[t] = f2bf(sv[t]);
        }
#pragma unroll
        for (int t = 0; t < 8; ++t) Vt[(size_t)(d8 + t) * STRV + j] = tv[t];
    }
    __syncthreads();

    const int lr = lane & 15;
    const int quad = lane >> 4;

    // ---- scores: S = Q @ Kw^T  (m=16 rows/wave, n=128, k=64) ----
    floatx4 sa[8];
#pragma unroll
    for (int nt = 0; nt < 8; ++nt) sa[nt] = (floatx4){0.f, 0.f, 0.f, 0.f};
    bf16x8 aq[2];
#pragma unroll
    for (int ks = 0; ks < 2; ++ks)
        aq[ks] = *(const bf16x8*)(Qs + (wid * 16 + lr) * STRQ + ks * 32 + quad * 8);
#pragma unroll
    for (int ks = 0; ks < 2; ++ks)
#pragma unroll
        for (int nt = 0; nt < 8; ++nt) {
            bf16x8 bk = *(const bf16x8*)(Kw + (nt * 16 + lr) * STRQ + ks * 32 + quad * 8);
            sa[nt] = __builtin_amdgcn_mfma_f32_16x16x32_bf16(aq[ks], bk, sa[nt], 0, 0, 0);
        }

    // ---- in-register masked softmax; write P (bf16) to LDS in A-layout ----
#pragma unroll
    for (int rr = 0; rr < 4; ++rr) {
        int i_loc = wid * 16 + quad * 4 + rr;   // local query index (0..63)
        float sv[8];
        float mv = -1e30f;
#pragma unroll
        for (int nt = 0; nt < 8; ++nt) {
            int j = nt * 16 + lr;
            int w = j - i_loc;
            sv[nt] = (w >= 0 && w < 64) ? sa[nt][rr] * 0.125f : -1e30f;
            mv = fmaxf(mv, sv[nt]);
        }
#pragma unroll
        for (int off = 8; off; off >>= 1) mv = fmaxf(mv, __shfl_xor(mv, off, 16));
        float sum = 0.f;
#pragma unroll
        for (int nt = 0; nt < 8; ++nt) {
            sv[nt] = __expf(sv[nt] - mv);
            sum += sv[nt];
        }
#pragma unroll
        for (int off = 8; off; off >>= 1) sum += __shfl_xor(sum, off, 16);
        float inv = 1.f / sum;
#pragma unroll
        for (int nt = 0; nt < 8; ++nt)
            Ps[(size_t)i_loc * STRV + nt * 16 + lr] = f2bf(sv[nt] * inv);
    }
    // PV reads only rows wid*16..+15 of Ps — written by this same wave; no barrier needed.

    // ---- O = P @ Vw  (as NT: B = Vt[d][j]) ----
    floatx4 oa[4];
#pragma unroll
    for (int nt = 0; nt < 4; ++nt) oa[nt] = (floatx4){0.f, 0.f, 0.f, 0.f};
#pragma unroll
    for (int ks = 0; ks < 4; ++ks) {
        bf16x8 ap = *(const bf16x8*)(Ps + (wid * 16 + lr) * STRV + ks * 32 + quad * 8);
#pragma unroll
        for (int nt = 0; nt < 4; ++nt) {
            bf16x8 bv = *(const bf16x8*)(Vt + (nt * 16 + lr) * STRV + ks * 32 + quad * 8);
            oa[nt] = __builtin_amdgcn_mfma_f32_16x16x32_bf16(ap, bv, oa[nt], 0, 0, 0);
        }
    }

    // ---- store O: ao[b][l0+i][h*64+d] bf16 ----
#pragma unroll
    for (int nt = 0; nt < 4; ++nt) {
        int d = nt * 16 + lr;
#pragma unroll
        for (int rr = 0; rr < 4; ++rr) {
            int i_loc = wid * 16 + quad * 4 + rr;
            ao[((size_t)b * 1024 + l0 + i_loc) * 1024 + h * 64 + d] = f2bf(oa[nt][rr]);
        }
    }
}

extern "C" void kernel_launch(void* const* d_in, const int* in_sizes, int n_in,
                              void* d_out, int out_size, void* d_ws, size_t ws_size,
                              hipStream_t stream) {
    const float* x     = (const float*)d_in[0];
    const float* Wq    = (const float*)d_in[1];
    const float* Wk    = (const float*)d_in[2];
    const float* Wv    = (const float*)d_in[3];
    const float* Wo    = (const float*)d_in[4];
    const float* lastk = (const float*)d_in[5];
    const float* lastv = (const float*)d_in[6];
    float* out = (float*)d_out;

    const size_t M1 = 1u << 20;
    ushort* xb  = (ushort*)d_ws;          // 2M
    ushort* wqb = xb + 2 * M1;            // 1M
    ushort* wkb = wqb + M1;
    ushort* wvb = wkb + M1;
    ushort* wob = wvb + M1;
    ushort* qh  = wob + M1;               // 2M each, head-major (B,H,L,DH)
    ushort* kh  = qh + 2 * M1;
    ushort* vh  = kh + 2 * M1;
    ushort* ao  = vh + 2 * M1;            // 2M, row-major (B,L,D)

    cvt_inputs<<<6144, 256, 0, stream>>>(x, Wq, Wk, Wv, Wo, xb, wqb, wkb, wvb, wob);
    gemm_qkv<<<dim3(16, 48), 256, 0, stream>>>(xb, wqb, wkb, wvb, qh, kh, vh);
    band_attn3<<<dim3(16, 32), 256, 0, stream>>>(qh, kh, vh, lastk, lastv, ao);
    gemm_wo<<<dim3(32, 16), 256, 0, stream>>>(ao, wob, out);
}